// Round 4
// baseline (498.522 us; speedup 1.0000x reference)
//
#include <hip/hip_runtime.h>

typedef __attribute__((ext_vector_type(8))) short short8;
typedef __attribute__((ext_vector_type(4))) float f32x4;
typedef unsigned short u16;
typedef unsigned int u32;

#define NH 16

#define EXP2(x) exp2f(x)

__device__ __forceinline__ u32 f2bf(float f) {
  u32 u = __builtin_bit_cast(u32, f);
  return (u + 0x7fffu + ((u >> 16) & 1u)) >> 16;  // round-nearest-even bf16 bits
}

// ---------- convert x + Wq,Wk,Wv,Wo (fp32) -> bf16 into ws ----------
__global__ __launch_bounds__(256) void k_convert(
    const float* __restrict__ x, const float* __restrict__ wq,
    const float* __restrict__ wk, const float* __restrict__ wv,
    const float* __restrict__ wo, u16* __restrict__ dst) {
  int i = blockIdx.x * 256 + threadIdx.x;
  size_t e = (size_t)i * 4;
  const float* s; size_t off;
  if (e < 8388608ull)       { s = x;  off = e; }
  else if (e < 9437184ull)  { s = wq; off = e - 8388608ull; }
  else if (e < 10485760ull) { s = wk; off = e - 9437184ull; }
  else if (e < 11534336ull) { s = wv; off = e - 10485760ull; }
  else                      { s = wo; off = e - 11534336ull; }
  float4 d = *(const float4*)(s + off);
  ushort4 o;
  o.x = (u16)f2bf(d.x); o.y = (u16)f2bf(d.y);
  o.z = (u16)f2bf(d.z); o.w = (u16)f2bf(d.w);
  *(ushort4*)(dst + e) = o;
}

// ---------- shared GEMM core: C[128x128] = A[128xK] * B[128xK]^T ----------
#define GEMM_CORE(Aptr, Bptr)                                                   \
  __shared__ u16 As[128 * 72];                                                  \
  __shared__ u16 Bs[128 * 72];                                                  \
  const int tid = threadIdx.x;                                                  \
  const int wave = tid >> 6, lane = tid & 63;                                   \
  const int wr = wave >> 1, wc = wave & 1;                                      \
  const int quad = lane >> 4, l16 = lane & 15;                                  \
  const int m0 = blockIdx.y * 128, n0 = blockIdx.x * 128;                       \
  f32x4 acc[4][4];                                                              \
  {                                                                             \
    f32x4 z = {0.f, 0.f, 0.f, 0.f};                                             \
    for (int a = 0; a < 4; ++a) for (int b2 = 0; b2 < 4; ++b2) acc[a][b2] = z;  \
  }                                                                             \
  for (int k0 = 0; k0 < 1024; k0 += 64) {                                       \
    _Pragma("unroll")                                                           \
    for (int i = 0; i < 4; ++i) {                                               \
      int c = i * 256 + tid;                                                    \
      int row = c >> 3, cc = c & 7;                                             \
      *(uint4*)(&As[row * 72 + cc * 8]) =                                       \
          *(const uint4*)(Aptr + (size_t)(m0 + row) * 1024 + k0 + cc * 8);      \
      *(uint4*)(&Bs[row * 72 + cc * 8]) =                                       \
          *(const uint4*)(Bptr + (size_t)(n0 + row) * 1024 + k0 + cc * 8);      \
    }                                                                           \
    __syncthreads();                                                            \
    _Pragma("unroll")                                                           \
    for (int ks = 0; ks < 2; ++ks) {                                            \
      short8 af[4], bfr[4];                                                     \
      _Pragma("unroll")                                                         \
      for (int t = 0; t < 4; ++t)                                               \
        af[t] = *(const short8*)(&As[(wr * 64 + t * 16 + l16) * 72 + ks * 32 + quad * 8]); \
      _Pragma("unroll")                                                         \
      for (int t = 0; t < 4; ++t)                                               \
        bfr[t] = *(const short8*)(&Bs[(wc * 64 + t * 16 + l16) * 72 + ks * 32 + quad * 8]); \
      _Pragma("unroll")                                                         \
      for (int mt = 0; mt < 4; ++mt) {                                          \
        _Pragma("unroll")                                                       \
        for (int nt = 0; nt < 4; ++nt)                                          \
          acc[mt][nt] = __builtin_amdgcn_mfma_f32_16x16x32_bf16(                \
              af[mt], bfr[nt], acc[mt][nt], 0, 0, 0);                           \
      }                                                                         \
    }                                                                           \
    __syncthreads();                                                            \
  }

// ---------- QKV projection: out scattered to [B,H,T,Dh] bf16 ----------
__global__ __launch_bounds__(256, 2) void k_gemm_qkv(
    const u16* __restrict__ A, const u16* __restrict__ W,
    const float* __restrict__ bq, const float* __restrict__ bk,
    const float* __restrict__ bv, u16* __restrict__ qkv) {
  const int z = blockIdx.z;
  const u16* Bw = W + (size_t)z * 1048576;
  const float* bias = (z == 0) ? bq : (z == 1) ? bk : bv;
  u16* out = qkv + (size_t)z * 8388608;
  GEMM_CORE(A, Bw)
  // q: fold 1/sqrt(64) AND log2(e) (attention softmax runs in exp2 domain)
  const float scl = (z == 0) ? 0.125f * 1.44269504088896340736f : 1.0f;
  #pragma unroll
  for (int mt = 0; mt < 4; ++mt) {
    #pragma unroll
    for (int nt = 0; nt < 4; ++nt) {
      int n = n0 + wc * 64 + nt * 16 + l16;
      float bn = bias[n];
      int h = n >> 6, d = n & 63;
      #pragma unroll
      for (int r = 0; r < 4; ++r) {
        int m = m0 + wr * 64 + mt * 16 + quad * 4 + r;
        int b = m >> 11, t = m & 2047;
        float val = (acc[mt][nt][r] + bn) * scl;
        out[(((size_t)(b * NH + h) * 2048 + t) << 6) + d] = (u16)f2bf(val);
      }
    }
  }
}

// ---------- output projection: fp32 out [8192][1024] ----------
__global__ __launch_bounds__(256, 2) void k_gemm_out(
    const u16* __restrict__ A, const u16* __restrict__ Bw,
    const float* __restrict__ bias, float* __restrict__ out) {
  GEMM_CORE(A, Bw)
  #pragma unroll
  for (int mt = 0; mt < 4; ++mt) {
    #pragma unroll
    for (int nt = 0; nt < 4; ++nt) {
      int n = n0 + wc * 64 + nt * 16 + l16;
      float bn = bias[n];
      #pragma unroll
      for (int r = 0; r < 4; ++r) {
        int m = m0 + wr * 64 + mt * 16 + quad * 4 + r;
        out[(size_t)m * 1024 + n] = acc[mt][nt][r] + bn;
      }
    }
  }
}

// ---------- V transpose: [B,H,T,Dh] -> [B,H,Dh,T] bf16 ----------
__global__ __launch_bounds__(256) void k_vtrans(const u16* __restrict__ v,
                                                u16* __restrict__ vt) {
  int t0 = blockIdx.x * 64;
  int bh = blockIdx.y;
  const u16* vs = v + (size_t)bh * 2048 * 64;
  u16* vd = vt + (size_t)bh * 64 * 2048;
  int tid = threadIdx.x;
  #pragma unroll
  for (int it = 0; it < 2; ++it) {
    int c = it * 256 + tid;
    int d = c >> 3, tc = c & 7;
    u16 tmp[8];
    #pragma unroll
    for (int j = 0; j < 8; ++j)
      tmp[j] = vs[(size_t)(t0 + tc * 8 + j) * 64 + d];
    uint4 pk;
    pk.x = (u32)tmp[0] | ((u32)tmp[1] << 16);
    pk.y = (u32)tmp[2] | ((u32)tmp[3] << 16);
    pk.z = (u32)tmp[4] | ((u32)tmp[5] << 16);
    pk.w = (u32)tmp[6] | ((u32)tmp[7] << 16);
    *(uint4*)(vd + (size_t)d * 2048 + t0 + tc * 8) = pk;
  }
}

// ---------- flash attention, S^T orientation, one q-tile per block --------
// S^T = K*Q^T puts q on lanes: softmax is serial-in-register + 2 shfl_xor;
// P packs to LDS via u32 bit-ops. Single q-tile keeps state under the
// (256,4) unified VGPR+AGPR cap of 128 -> NO spills (R3's paired variant
// spilled ~280 MB of scratch). Load balance via LPT: qt = 31 - bx so the
// longest blocks dispatch first and short ones backfill the tail.
#define ATTN_STEP(QF0, QF1, O, MI, LI, PW, DIAG)                               \
  {                                                                            \
    f32x4 st[4];                                                               \
    _Pragma("unroll")                                                          \
    for (int nt = 0; nt < 4; ++nt) {                                           \
      short8 kf0 = *(const short8*)(&Ks[(nt * 16 + l16) * 72 + quad * 8]);     \
      short8 kf1 = *(const short8*)(&Ks[(nt * 16 + l16) * 72 + 32 + quad * 8]);\
      f32x4 z4 = {0.f, 0.f, 0.f, 0.f};                                         \
      z4 = __builtin_amdgcn_mfma_f32_16x16x32_bf16(kf0, QF0, z4, 0, 0, 0);     \
      st[nt] = __builtin_amdgcn_mfma_f32_16x16x32_bf16(kf1, QF1, z4, 0, 0, 0); \
    }                                                                          \
    if (DIAG) {                                                                \
      int q_loc = wave * 16 + l16;                                             \
      _Pragma("unroll")                                                        \
      for (int nt = 0; nt < 4; ++nt) {                                         \
        _Pragma("unroll")                                                      \
        for (int r = 0; r < 4; ++r) {                                          \
          int k_loc = nt * 16 + quad * 4 + r;                                  \
          if (k_loc > q_loc) st[nt][r] = -1e30f;                               \
        }                                                                      \
      }                                                                        \
    }                                                                          \
    float mx = -1e30f;                                                         \
    _Pragma("unroll")                                                          \
    for (int nt = 0; nt < 4; ++nt)                                             \
      _Pragma("unroll")                                                        \
      for (int r = 0; r < 4; ++r) mx = fmaxf(mx, st[nt][r]);                   \
    mx = fmaxf(mx, __shfl_xor(mx, 16, 64));                                    \
    mx = fmaxf(mx, __shfl_xor(mx, 32, 64));                                    \
    float mnew = fmaxf(MI, mx);                                                \
    float alpha = EXP2(MI - mnew);                                             \
    MI = mnew;                                                                 \
    float sum = 0.f;                                                           \
    _Pragma("unroll")                                                          \
    for (int nt = 0; nt < 4; ++nt) {                                           \
      float p0 = EXP2(st[nt][0] - mnew);                                       \
      float p1 = EXP2(st[nt][1] - mnew);                                       \
      float p2 = EXP2(st[nt][2] - mnew);                                       \
      float p3 = EXP2(st[nt][3] - mnew);                                       \
      sum += p0 + p1 + p2 + p3;                                                \
      uint2 pk;                                                                \
      pk.x = f2bf(p0) | (f2bf(p1) << 16);                                      \
      pk.y = f2bf(p2) | (f2bf(p3) << 16);                                      \
      *(uint2*)(&PW[l16 * 72 + nt * 16 + quad * 4]) = pk;                      \
    }                                                                          \
    sum += __shfl_xor(sum, 16, 64);                                            \
    sum += __shfl_xor(sum, 32, 64);                                            \
    LI = LI * alpha + sum;                                                     \
    _Pragma("unroll")                                                          \
    for (int r = 0; r < 4; ++r) {                                              \
      float av = __shfl(alpha, quad * 4 + r, 16);                              \
      _Pragma("unroll")                                                        \
      for (int dt = 0; dt < 4; ++dt) O[dt][r] *= av;                           \
    }                                                                          \
    _Pragma("unroll")                                                          \
    for (int ks = 0; ks < 2; ++ks) {                                           \
      short8 pf = *(const short8*)(PW + l16 * 72 + ks * 32 + quad * 8);        \
      _Pragma("unroll")                                                        \
      for (int dt = 0; dt < 4; ++dt) {                                         \
        short8 vf = *(const short8*)(&Vs[(dt * 16 + l16) * 72 + ks * 32 + quad * 8]); \
        O[dt] = __builtin_amdgcn_mfma_f32_16x16x32_bf16(pf, vf, O[dt], 0, 0, 0); \
      }                                                                        \
    }                                                                          \
  }

__global__ __launch_bounds__(256, 4) void k_attn(
    const u16* __restrict__ q, const u16* __restrict__ k,
    const u16* __restrict__ vt, u16* __restrict__ y) {
  const int tid = threadIdx.x;
  const int wave = tid >> 6, lane = tid & 63;
  const int quad = lane >> 4, l16 = lane & 15;
  const int qt = 31 - blockIdx.x;      // LPT: longest q-tiles dispatch first
  const int bh = blockIdx.y;
  const int b = bh >> 4, h = bh & 15;

  __shared__ u16 Ks[64 * 72];
  __shared__ u16 Vs[64 * 72];           // [d][kidx]
  __shared__ u16 Ps[4 * 16 * 72];       // per-wave 16 q-rows x 64 k

  const u16* qb = q + ((size_t)bh * 2048 + qt * 64 + wave * 16 + l16) * 64;
  short8 qf0 = *(const short8*)(qb + quad * 8);
  short8 qf1 = *(const short8*)(qb + 32 + quad * 8);

  f32x4 o[4];
  { f32x4 z = {0.f,0.f,0.f,0.f}; for (int dt = 0; dt < 4; ++dt) o[dt] = z; }
  float m_i = -1e30f, l_i = 0.f;        // per-lane: row q = l16 (repl. quads)

  u16* pw = Ps + wave * 16 * 72;
  const u16* kbase = k + (size_t)bh * 2048 * 64;
  const u16* vbase = vt + (size_t)bh * 64 * 2048;
  const int r0 = tid >> 3, cc = tid & 7;

  uint4 kr[2], vr[2];
  #pragma unroll
  for (int i = 0; i < 2; ++i) {
    int row = i * 32 + r0;
    kr[i] = *(const uint4*)(kbase + (size_t)row * 64 + cc * 8);
    vr[i] = *(const uint4*)(vbase + (size_t)row * 2048 + cc * 8);
  }

  for (int kt = 0; kt <= qt; ++kt) {
    #pragma unroll
    for (int i = 0; i < 2; ++i) {
      int row = i * 32 + r0;
      *(uint4*)(&Ks[row * 72 + cc * 8]) = kr[i];
      *(uint4*)(&Vs[row * 72 + cc * 8]) = vr[i];
    }
    __syncthreads();

    if (kt < qt) {  // register-prefetch next K/V tile across the compute
      const u16* kb = kbase + (size_t)(kt + 1) * 64 * 64;
      const u16* vb = vbase + (kt + 1) * 64;
      #pragma unroll
      for (int i = 0; i < 2; ++i) {
        int row = i * 32 + r0;
        kr[i] = *(const uint4*)(kb + (size_t)row * 64 + cc * 8);
        vr[i] = *(const uint4*)(vb + (size_t)row * 2048 + cc * 8);
      }
    }

    ATTN_STEP(qf0, qf1, o, m_i, l_i, pw, (kt == qt))
    __syncthreads();
  }

  // epilogue: y[b][t][h][d] = O / l   (l lives on lane l16 = q -> broadcast)
  #pragma unroll
  for (int r = 0; r < 4; ++r) {
    float lv = __shfl(l_i, quad * 4 + r, 16);
    float inv = 1.0f / lv;
    int t = qt * 64 + wave * 16 + quad * 4 + r;
    #pragma unroll
    for (int dt = 0; dt < 4; ++dt) {
      int d = dt * 16 + l16;
      y[(((size_t)b * 2048 + t) * NH + h) * 64 + d] = (u16)f2bf(o[dt][r] * inv);
    }
  }
}

extern "C" void kernel_launch(void* const* d_in, const int* in_sizes, int n_in,
                              void* d_out, int out_size, void* d_ws, size_t ws_size,
                              hipStream_t stream) {
  const float* x  = (const float*)d_in[0];
  const float* Wq = (const float*)d_in[1];
  const float* bq = (const float*)d_in[2];
  const float* Wk = (const float*)d_in[3];
  const float* bk = (const float*)d_in[4];
  const float* Wv = (const float*)d_in[5];
  const float* bv = (const float*)d_in[6];
  const float* Wo = (const float*)d_in[7];
  const float* bo = (const float*)d_in[8];
  float* out = (float*)d_out;

  u16* ws  = (u16*)d_ws;
  u16* xb  = ws;                   // 8388608   x bf16 [8192][1024]
  u16* Wb  = ws + 8388608;         // 4x1048576 Wq|Wk|Wv|Wo bf16
  u16* qkv = ws + 12582912;        // 3x8388608 q|k|v [B,H,T,Dh] bf16
  u16* vt  = ws + 37748736;        // 8388608   v^T [B,H,Dh,T] bf16
  u16* y   = ws + 46137344;        // 8388608   attn out [B,T,H,Dh] bf16

  k_convert<<<dim3(12288), dim3(256), 0, stream>>>(x, Wq, Wk, Wv, Wo, ws);
  k_gemm_qkv<<<dim3(8, 64, 3), dim3(256), 0, stream>>>(xb, Wb, bq, bk, bv, qkv);
  k_vtrans<<<dim3(32, 64), dim3(256), 0, stream>>>(qkv + 2 * 8388608, vt);
  k_attn<<<dim3(32, 64), dim3(256), 0, stream>>>(qkv, qkv + 8388608, vt, y);
  k_gemm_out<<<dim3(8, 64), dim3(256), 0, stream>>>(y, Wb + 3 * 1048576, bo, out);
}

// Round 5
// 373.041 us; speedup vs baseline: 1.3364x; 1.3364x over previous
//
#include <hip/hip_runtime.h>

typedef __attribute__((ext_vector_type(8))) short short8;
typedef __attribute__((ext_vector_type(4))) float f32x4;
typedef unsigned short u16;
typedef unsigned int u32;

#define NH 16

__device__ __forceinline__ u32 f2bf(float f) {
  u32 u = __builtin_bit_cast(u32, f);
  return (u + 0x7fffu + ((u >> 16) & 1u)) >> 16;  // round-nearest-even bf16 bits
}

// ---------- convert x + Wq,Wk,Wv,Wo (fp32) -> bf16 into ws ----------
__global__ __launch_bounds__(256) void k_convert(
    const float* __restrict__ x, const float* __restrict__ wq,
    const float* __restrict__ wk, const float* __restrict__ wv,
    const float* __restrict__ wo, u16* __restrict__ dst) {
  int i = blockIdx.x * 256 + threadIdx.x;
  size_t e = (size_t)i * 4;
  const float* s; size_t off;
  if (e < 8388608ull)       { s = x;  off = e; }
  else if (e < 9437184ull)  { s = wq; off = e - 8388608ull; }
  else if (e < 10485760ull) { s = wk; off = e - 9437184ull; }
  else if (e < 11534336ull) { s = wv; off = e - 10485760ull; }
  else                      { s = wo; off = e - 11534336ull; }
  float4 d = *(const float4*)(s + off);
  ushort4 o;
  o.x = (u16)f2bf(d.x); o.y = (u16)f2bf(d.y);
  o.z = (u16)f2bf(d.z); o.w = (u16)f2bf(d.w);
  *(ushort4*)(dst + e) = o;
}

// ---------- shared GEMM core: C[128x128] = A[128xK] * B[128xK]^T ----------
#define GEMM_CORE(Aptr, Bptr)                                                   \
  __shared__ u16 As[128 * 72];                                                  \
  __shared__ u16 Bs[128 * 72];                                                  \
  const int tid = threadIdx.x;                                                  \
  const int wave = tid >> 6, lane = tid & 63;                                   \
  const int wr = wave >> 1, wc = wave & 1;                                      \
  const int quad = lane >> 4, l16 = lane & 15;                                  \
  const int m0 = blockIdx.y * 128, n0 = blockIdx.x * 128;                       \
  f32x4 acc[4][4];                                                              \
  {                                                                             \
    f32x4 z = {0.f, 0.f, 0.f, 0.f};                                             \
    for (int a = 0; a < 4; ++a) for (int b2 = 0; b2 < 4; ++b2) acc[a][b2] = z;  \
  }                                                                             \
  for (int k0 = 0; k0 < 1024; k0 += 64) {                                       \
    _Pragma("unroll")                                                           \
    for (int i = 0; i < 4; ++i) {                                               \
      int c = i * 256 + tid;                                                    \
      int row = c >> 3, cc = c & 7;                                             \
      *(uint4*)(&As[row * 72 + cc * 8]) =                                       \
          *(const uint4*)(Aptr + (size_t)(m0 + row) * 1024 + k0 + cc * 8);      \
      *(uint4*)(&Bs[row * 72 + cc * 8]) =                                       \
          *(const uint4*)(Bptr + (size_t)(n0 + row) * 1024 + k0 + cc * 8);      \
    }                                                                           \
    __syncthreads();                                                            \
    _Pragma("unroll")                                                           \
    for (int ks = 0; ks < 2; ++ks) {                                            \
      short8 af[4], bfr[4];                                                     \
      _Pragma("unroll")                                                         \
      for (int t = 0; t < 4; ++t)                                               \
        af[t] = *(const short8*)(&As[(wr * 64 + t * 16 + l16) * 72 + ks * 32 + quad * 8]); \
      _Pragma("unroll")                                                         \
      for (int t = 0; t < 4; ++t)                                               \
        bfr[t] = *(const short8*)(&Bs[(wc * 64 + t * 16 + l16) * 72 + ks * 32 + quad * 8]); \
      _Pragma("unroll")                                                         \
      for (int mt = 0; mt < 4; ++mt) {                                          \
        _Pragma("unroll")                                                       \
        for (int nt = 0; nt < 4; ++nt)                                          \
          acc[mt][nt] = __builtin_amdgcn_mfma_f32_16x16x32_bf16(                \
              af[mt], bfr[nt], acc[mt][nt], 0, 0, 0);                           \
      }                                                                         \
    }                                                                           \
    __syncthreads();                                                            \
  }

// ---------- QKV projection: out scattered to [B,H,T,Dh] bf16 ----------
__global__ __launch_bounds__(256, 2) void k_gemm_qkv(
    const u16* __restrict__ A, const u16* __restrict__ W,
    const float* __restrict__ bq, const float* __restrict__ bk,
    const float* __restrict__ bv, u16* __restrict__ qkv) {
  const int z = blockIdx.z;
  const u16* Bw = W + (size_t)z * 1048576;
  const float* bias = (z == 0) ? bq : (z == 1) ? bk : bv;
  u16* out = qkv + (size_t)z * 8388608;
  GEMM_CORE(A, Bw)
  // q: fold 1/sqrt(64) AND log2(e) (attention softmax runs in exp2 domain)
  const float scl = (z == 0) ? 0.125f * 1.44269504088896340736f : 1.0f;
  #pragma unroll
  for (int mt = 0; mt < 4; ++mt) {
    #pragma unroll
    for (int nt = 0; nt < 4; ++nt) {
      int n = n0 + wc * 64 + nt * 16 + l16;
      float bn = bias[n];
      int h = n >> 6, d = n & 63;
      #pragma unroll
      for (int r = 0; r < 4; ++r) {
        int m = m0 + wr * 64 + mt * 16 + quad * 4 + r;
        int b = m >> 11, t = m & 2047;
        float val = (acc[mt][nt][r] + bn) * scl;
        out[(((size_t)(b * NH + h) * 2048 + t) << 6) + d] = (u16)f2bf(val);
      }
    }
  }
}

// ---------- output projection: fp32 out [8192][1024] ----------
__global__ __launch_bounds__(256, 2) void k_gemm_out(
    const u16* __restrict__ A, const u16* __restrict__ Bw,
    const float* __restrict__ bias, float* __restrict__ out) {
  GEMM_CORE(A, Bw)
  #pragma unroll
  for (int mt = 0; mt < 4; ++mt) {
    #pragma unroll
    for (int nt = 0; nt < 4; ++nt) {
      int n = n0 + wc * 64 + nt * 16 + l16;
      float bn = bias[n];
      #pragma unroll
      for (int r = 0; r < 4; ++r) {
        int m = m0 + wr * 64 + mt * 16 + quad * 4 + r;
        out[(size_t)m * 1024 + n] = acc[mt][nt][r] + bn;
      }
    }
  }
}

// ---------- V transpose: [B,H,T,Dh] -> [B,H,Dh,T] bf16 ----------
__global__ __launch_bounds__(256) void k_vtrans(const u16* __restrict__ v,
                                                u16* __restrict__ vt) {
  int t0 = blockIdx.x * 64;
  int bh = blockIdx.y;
  const u16* vs = v + (size_t)bh * 2048 * 64;
  u16* vd = vt + (size_t)bh * 64 * 2048;
  int tid = threadIdx.x;
  #pragma unroll
  for (int it = 0; it < 2; ++it) {
    int c = it * 256 + tid;
    int d = c >> 3, tc = c & 7;
    u16 tmp[8];
    #pragma unroll
    for (int j = 0; j < 8; ++j)
      tmp[j] = vs[(size_t)(t0 + tc * 8 + j) * 64 + d];
    uint4 pk;
    pk.x = (u32)tmp[0] | ((u32)tmp[1] << 16);
    pk.y = (u32)tmp[2] | ((u32)tmp[3] << 16);
    pk.z = (u32)tmp[4] | ((u32)tmp[5] << 16);
    pk.w = (u32)tmp[6] | ((u32)tmp[7] << 16);
    *(uint4*)(vd + (size_t)d * 2048 + t0 + tc * 8) = pk;
  }
}

// ---------- flash attention, S^T orientation, R1-vintage codegen ----------
// All hot code in-body (no macros), plain #pragma unroll, scalar u16 P
// stores, no register-prefetch arrays, no width-16 shfl (alpha/l cross-
// layout broadcast goes through tiny per-wave LDS arrays). These constraints
// exist because R2-R4 variants generated ~200 MB/dispatch of scratch traffic
// (WRITE_SIZE 160-298 MB vs legit 16 MB); R1-style code measured clean.
// S^T = K*Q^T puts q on lanes: row softmax = serial in-register + 2 shfl_xor.
// LPT: qt = 31 - bx so the heaviest blocks dispatch first.
__global__ __launch_bounds__(256, 2) void k_attn(
    const u16* __restrict__ q, const u16* __restrict__ k,
    const u16* __restrict__ vt, u16* __restrict__ y) {
  const int tid = threadIdx.x;
  const int wave = tid >> 6, lane = tid & 63;
  const int quad = lane >> 4, l16 = lane & 15;
  const int qt = 31 - (int)blockIdx.x;  // LPT order
  const int bh = blockIdx.y;
  const int b = bh >> 4, h = bh & 15;

  __shared__ u16 Ks[64 * 72];
  __shared__ u16 Vs[64 * 72];           // [d][kidx]
  __shared__ u16 Ps[4 * 16 * 72];       // per-wave 16 q-rows x 64 k
  __shared__ float Bc[4][16];           // per-wave alpha broadcast (q-indexed)
  __shared__ float Lc[4][16];           // per-wave l broadcast (epilogue)

  // Q fragments (B-operand: n = q row = wave*16 + l16) live in registers.
  const u16* qb = q + ((size_t)bh * 2048 + qt * 64 + wave * 16 + l16) * 64;
  short8 qf0 = *(const short8*)(qb + quad * 8);
  short8 qf1 = *(const short8*)(qb + 32 + quad * 8);

  f32x4 o[4];
  { f32x4 z = {0.f,0.f,0.f,0.f}; for (int dt = 0; dt < 4; ++dt) o[dt] = z; }
  float m_i = -1e30f, l_i = 0.f;        // per-lane softmax state for q = l16

  u16* pw = Ps + wave * 16 * 72;
  const u16* kbase = k + (size_t)bh * 2048 * 64;
  const u16* vbase = vt + (size_t)bh * 64 * 2048;

  for (int kt = 0; kt <= qt; ++kt) {
    const u16* kb = kbase + (size_t)kt * 64 * 64;
    const u16* vb = vbase + kt * 64;
    #pragma unroll
    for (int i = 0; i < 2; ++i) {
      int c = i * 256 + tid;
      int row = c >> 3, cc = c & 7;
      *(uint4*)(&Ks[row * 72 + cc * 8]) = *(const uint4*)(kb + (size_t)row * 64 + cc * 8);
      *(uint4*)(&Vs[row * 72 + cc * 8]) = *(const uint4*)(vb + (size_t)row * 2048 + cc * 8);
    }
    __syncthreads();

    // S^T = K Q^T : D[m = k-idx (quad,reg)][n = q row (l16)]
    f32x4 st[4];
    #pragma unroll
    for (int nt = 0; nt < 4; ++nt) {
      short8 kf0 = *(const short8*)(&Ks[(nt * 16 + l16) * 72 + quad * 8]);
      short8 kf1 = *(const short8*)(&Ks[(nt * 16 + l16) * 72 + 32 + quad * 8]);
      f32x4 z4 = {0.f, 0.f, 0.f, 0.f};
      z4 = __builtin_amdgcn_mfma_f32_16x16x32_bf16(kf0, qf0, z4, 0, 0, 0);
      st[nt] = __builtin_amdgcn_mfma_f32_16x16x32_bf16(kf1, qf1, z4, 0, 0, 0);
    }

    if (kt == qt) {  // diagonal tile causal mask
      int q_loc = wave * 16 + l16;
      #pragma unroll
      for (int nt = 0; nt < 4; ++nt) {
        #pragma unroll
        for (int r = 0; r < 4; ++r) {
          int k_loc = nt * 16 + quad * 4 + r;
          if (k_loc > q_loc) st[nt][r] = -1e30f;
        }
      }
    }

    // online softmax for row q = l16 (replicated across quads)
    float mx = -1e30f;
    #pragma unroll
    for (int nt = 0; nt < 4; ++nt)
      #pragma unroll
      for (int r = 0; r < 4; ++r) mx = fmaxf(mx, st[nt][r]);
    mx = fmaxf(mx, __shfl_xor(mx, 16));
    mx = fmaxf(mx, __shfl_xor(mx, 32));
    float mnew = fmaxf(m_i, mx);
    float alpha = exp2f(m_i - mnew);
    m_i = mnew;
    Bc[wave][l16] = alpha;  // all quads store the same value: benign

    float sum = 0.f;
    #pragma unroll
    for (int nt = 0; nt < 4; ++nt) {
      #pragma unroll
      for (int r = 0; r < 4; ++r) {
        float p = exp2f(st[nt][r] - mnew);
        sum += p;
        pw[l16 * 72 + nt * 16 + quad * 4 + r] = (u16)f2bf(p);  // A-layout
      }
    }
    sum += __shfl_xor(sum, 16);
    sum += __shfl_xor(sum, 32);
    l_i = l_i * alpha + sum;

    // rescale O rows (q = quad*4+r) by alpha via LDS broadcast
    #pragma unroll
    for (int r = 0; r < 4; ++r) {
      float av = Bc[wave][quad * 4 + r];
      #pragma unroll
      for (int dt = 0; dt < 4; ++dt) o[dt][r] *= av;
    }

    // O += P * V : A=P (m=q on l16), B=V^T (n=d on l16)
    #pragma unroll
    for (int ks = 0; ks < 2; ++ks) {
      short8 pf = *(const short8*)(pw + l16 * 72 + ks * 32 + quad * 8);
      #pragma unroll
      for (int dt = 0; dt < 4; ++dt) {
        short8 vf = *(const short8*)(&Vs[(dt * 16 + l16) * 72 + ks * 32 + quad * 8]);
        o[dt] = __builtin_amdgcn_mfma_f32_16x16x32_bf16(pf, vf, o[dt], 0, 0, 0);
      }
    }
    __syncthreads();
  }

  // epilogue: y[b][t][h][d] = O / l  (l broadcast q-lanes -> (quad,reg) rows)
  Lc[wave][l16] = l_i;
  #pragma unroll
  for (int r = 0; r < 4; ++r) {
    float inv = 1.0f / Lc[wave][quad * 4 + r];
    int t = qt * 64 + wave * 16 + quad * 4 + r;
    #pragma unroll
    for (int dt = 0; dt < 4; ++dt) {
      int d = dt * 16 + l16;
      y[(((size_t)b * 2048 + t) * NH + h) * 64 + d] = (u16)f2bf(o[dt][r] * inv);
    }
  }
}

extern "C" void kernel_launch(void* const* d_in, const int* in_sizes, int n_in,
                              void* d_out, int out_size, void* d_ws, size_t ws_size,
                              hipStream_t stream) {
  const float* x  = (const float*)d_in[0];
  const float* Wq = (const float*)d_in[1];
  const float* bq = (const float*)d_in[2];
  const float* Wk = (const float*)d_in[3];
  const float* bk = (const float*)d_in[4];
  const float* Wv = (const float*)d_in[5];
  const float* bv = (const float*)d_in[6];
  const float* Wo = (const float*)d_in[7];
  const float* bo = (const float*)d_in[8];
  float* out = (float*)d_out;

  u16* ws  = (u16*)d_ws;
  u16* xb  = ws;                   // 8388608   x bf16 [8192][1024]
  u16* Wb  = ws + 8388608;         // 4x1048576 Wq|Wk|Wv|Wo bf16
  u16* qkv = ws + 12582912;        // 3x8388608 q|k|v [B,H,T,Dh] bf16
  u16* vt  = ws + 37748736;        // 8388608   v^T [B,H,Dh,T] bf16
  u16* y   = ws + 46137344;        // 8388608   attn out [B,T,H,Dh] bf16

  k_convert<<<dim3(12288), dim3(256), 0, stream>>>(x, Wq, Wk, Wv, Wo, ws);
  k_gemm_qkv<<<dim3(8, 64, 3), dim3(256), 0, stream>>>(xb, Wb, bq, bk, bv, qkv);
  k_vtrans<<<dim3(32, 64), dim3(256), 0, stream>>>(qkv + 2 * 8388608, vt);
  k_attn<<<dim3(32, 64), dim3(256), 0, stream>>>(qkv, qkv + 8388608, vt, y);
  k_gemm_out<<<dim3(8, 64), dim3(256), 0, stream>>>(y, Wb + 3 * 1048576, bo, out);
}

// Round 6
// 370.143 us; speedup vs baseline: 1.3468x; 1.0078x over previous
//
#include <hip/hip_runtime.h>

typedef __attribute__((ext_vector_type(8))) short short8;
typedef __attribute__((ext_vector_type(4))) float f32x4;
typedef unsigned short u16;
typedef unsigned int u32;

#define NH 16

__device__ __forceinline__ u32 f2bf(float f) {        // round-nearest-even
  u32 u = __builtin_bit_cast(u32, f);
  return (u + 0x7fffu + ((u >> 16) & 1u)) >> 16;
}
__device__ __forceinline__ u32 f2bf_hu(float f) {     // round-half-up (hot path)
  u32 u = __builtin_bit_cast(u32, f);
  return (u + 0x8000u) >> 16;
}

// async global->LDS, 16B per lane (wave-uniform LDS base + lane*16)
__device__ __forceinline__ void async16(const u16* g, u16* l) {
  __builtin_amdgcn_global_load_lds(
      (const __attribute__((address_space(1))) u32*)g,
      (__attribute__((address_space(3))) u32*)l, 16, 0, 0);
}

// ---------- convert x + Wq,Wk,Wv,Wo (fp32) -> bf16 into ws ----------
__global__ __launch_bounds__(256) void k_convert(
    const float* __restrict__ x, const float* __restrict__ wq,
    const float* __restrict__ wk, const float* __restrict__ wv,
    const float* __restrict__ wo, u16* __restrict__ dst) {
  int i = blockIdx.x * 256 + threadIdx.x;
  size_t e = (size_t)i * 4;
  const float* s; size_t off;
  if (e < 8388608ull)       { s = x;  off = e; }
  else if (e < 9437184ull)  { s = wq; off = e - 8388608ull; }
  else if (e < 10485760ull) { s = wk; off = e - 9437184ull; }
  else if (e < 11534336ull) { s = wv; off = e - 10485760ull; }
  else                      { s = wo; off = e - 11534336ull; }
  float4 d = *(const float4*)(s + off);
  ushort4 o;
  o.x = (u16)f2bf(d.x); o.y = (u16)f2bf(d.y);
  o.z = (u16)f2bf(d.z); o.w = (u16)f2bf(d.w);
  *(ushort4*)(dst + e) = o;
}

// ---------- shared GEMM core (m97-style): C[128x128] = A * B^T ----------
// global_load_lds width=16 staging into UNPADDED LDS (128x64 u16 per tile);
// chunk c (16B) lands at LDS offset c*16 = row-major [row][col] exactly.
#define GEMM_CORE(Aptr, Bptr)                                                   \
  __shared__ u16 As[128 * 64];                                                  \
  __shared__ u16 Bs[128 * 64];                                                  \
  const int tid = threadIdx.x;                                                  \
  const int wave = tid >> 6, lane = tid & 63;                                   \
  const int wr = wave >> 1, wc = wave & 1;                                      \
  const int quad = lane >> 4, l16 = lane & 15;                                  \
  const int m0 = blockIdx.y * 128, n0 = blockIdx.x * 128;                       \
  f32x4 acc[4][4];                                                              \
  {                                                                             \
    f32x4 z = {0.f, 0.f, 0.f, 0.f};                                             \
    for (int a = 0; a < 4; ++a) for (int b2 = 0; b2 < 4; ++b2) acc[a][b2] = z;  \
  }                                                                             \
  for (int k0 = 0; k0 < 1024; k0 += 64) {                                       \
    _Pragma("unroll")                                                           \
    for (int i = 0; i < 4; ++i) {                                               \
      int c = i * 256 + tid;                                                    \
      int row = c >> 3, cc = c & 7;                                             \
      async16(Aptr + (size_t)(m0 + row) * 1024 + k0 + cc * 8, &As[c * 8]);      \
      async16(Bptr + (size_t)(n0 + row) * 1024 + k0 + cc * 8, &Bs[c * 8]);      \
    }                                                                           \
    __syncthreads();                                                            \
    _Pragma("unroll")                                                           \
    for (int ks = 0; ks < 2; ++ks) {                                            \
      short8 af[4], bfr[4];                                                     \
      _Pragma("unroll")                                                         \
      for (int t = 0; t < 4; ++t)                                               \
        af[t] = *(const short8*)(&As[(wr * 64 + t * 16 + l16) * 64 + ks * 32 + quad * 8]); \
      _Pragma("unroll")                                                         \
      for (int t = 0; t < 4; ++t)                                               \
        bfr[t] = *(const short8*)(&Bs[(wc * 64 + t * 16 + l16) * 64 + ks * 32 + quad * 8]); \
      _Pragma("unroll")                                                         \
      for (int mt = 0; mt < 4; ++mt) {                                          \
        _Pragma("unroll")                                                       \
        for (int nt = 0; nt < 4; ++nt)                                          \
          acc[mt][nt] = __builtin_amdgcn_mfma_f32_16x16x32_bf16(                \
              af[mt], bfr[nt], acc[mt][nt], 0, 0, 0);                           \
      }                                                                         \
    }                                                                           \
    __syncthreads();                                                            \
  }

// ---------- QKV projection: out scattered to [B,H,T,Dh] bf16 ----------
__global__ __launch_bounds__(256, 2) void k_gemm_qkv(
    const u16* __restrict__ A, const u16* __restrict__ W,
    const float* __restrict__ bq, const float* __restrict__ bk,
    const float* __restrict__ bv, u16* __restrict__ qkv) {
  const int z = blockIdx.z;
  const u16* Bw = W + (size_t)z * 1048576;
  const float* bias = (z == 0) ? bq : (z == 1) ? bk : bv;
  u16* out = qkv + (size_t)z * 8388608;
  GEMM_CORE(A, Bw)
  // q: fold 1/sqrt(64) AND log2(e) (attention softmax runs in exp2 domain)
  const float scl = (z == 0) ? 0.125f * 1.44269504088896340736f : 1.0f;
  #pragma unroll
  for (int mt = 0; mt < 4; ++mt) {
    #pragma unroll
    for (int nt = 0; nt < 4; ++nt) {
      int n = n0 + wc * 64 + nt * 16 + l16;
      float bn = bias[n];
      int h = n >> 6, d = n & 63;
      #pragma unroll
      for (int r = 0; r < 4; ++r) {
        int m = m0 + wr * 64 + mt * 16 + quad * 4 + r;
        int b = m >> 11, t = m & 2047;
        float val = (acc[mt][nt][r] + bn) * scl;
        out[(((size_t)(b * NH + h) * 2048 + t) << 6) + d] = (u16)f2bf(val);
      }
    }
  }
}

// ---------- output projection: fp32 out [8192][1024] ----------
__global__ __launch_bounds__(256, 2) void k_gemm_out(
    const u16* __restrict__ A, const u16* __restrict__ Bw,
    const float* __restrict__ bias, float* __restrict__ out) {
  GEMM_CORE(A, Bw)
  #pragma unroll
  for (int mt = 0; mt < 4; ++mt) {
    #pragma unroll
    for (int nt = 0; nt < 4; ++nt) {
      int n = n0 + wc * 64 + nt * 16 + l16;
      float bn = bias[n];
      #pragma unroll
      for (int r = 0; r < 4; ++r) {
        int m = m0 + wr * 64 + mt * 16 + quad * 4 + r;
        out[(size_t)m * 1024 + n] = acc[mt][nt][r] + bn;
      }
    }
  }
}

// ---------- V transpose: [B,H,T,Dh] -> [B,H,Dh,T] bf16 ----------
__global__ __launch_bounds__(256) void k_vtrans(const u16* __restrict__ v,
                                                u16* __restrict__ vt) {
  int t0 = blockIdx.x * 64;
  int bh = blockIdx.y;
  const u16* vs = v + (size_t)bh * 2048 * 64;
  u16* vd = vt + (size_t)bh * 64 * 2048;
  int tid = threadIdx.x;
  #pragma unroll
  for (int it = 0; it < 2; ++it) {
    int c = it * 256 + tid;
    int d = c >> 3, tc = c & 7;
    u16 tmp[8];
    #pragma unroll
    for (int j = 0; j < 8; ++j)
      tmp[j] = vs[(size_t)(t0 + tc * 8 + j) * 64 + d];
    uint4 pk;
    pk.x = (u32)tmp[0] | ((u32)tmp[1] << 16);
    pk.y = (u32)tmp[2] | ((u32)tmp[3] << 16);
    pk.z = (u32)tmp[4] | ((u32)tmp[5] << 16);
    pk.w = (u32)tmp[6] | ((u32)tmp[7] << 16);
    *(uint4*)(vd + (size_t)d * 2048 + t0 + tc * 8) = pk;
  }
}

// ---------- flash attention: 128 q-rows/block, 2 q-groups per wave --------
// S^T = K*Q^T (q on lanes). Two INDEPENDENT chains per wave (groups A/B =
// q-rows [0,64) and [64,128) of the block) double ILP and halve staging +
// barriers per unit work. R1-vintage codegen rules (in-body, plain unroll,
// scalar u16 P stores, LDS broadcasts) — R2-R4 showed fancier constructs
// generate ~200 MB of scratch. LPT: qt = 15 - bx.
__global__ __launch_bounds__(256, 3) void k_attn(
    const u16* __restrict__ q, const u16* __restrict__ k,
    const u16* __restrict__ vt, u16* __restrict__ y) {
  const int tid = threadIdx.x;
  const int wave = tid >> 6, lane = tid & 63;
  const int quad = lane >> 4, l16 = lane & 15;
  const int qt = 15 - (int)blockIdx.x;  // 128-row q block, LPT order
  const int bh = blockIdx.y;
  const int b = bh >> 4, h = bh & 15;

  __shared__ u16 Ks[64 * 72];
  __shared__ u16 Vs[64 * 72];             // [d][kidx]
  __shared__ u16 Ps[4 * 2 * 16 * 72];     // per wave x group: 16 q-rows x 64 k
  __shared__ float Bc[4][2][16];          // alpha broadcast
  __shared__ float Lc[4][2][16];          // l broadcast (epilogue)

  const u16* qbA = q + ((size_t)bh * 2048 + qt * 128 + wave * 16 + l16) * 64;
  const u16* qbB = qbA + 64 * 64;
  short8 qA0 = *(const short8*)(qbA + quad * 8);
  short8 qA1 = *(const short8*)(qbA + 32 + quad * 8);
  short8 qB0 = *(const short8*)(qbB + quad * 8);
  short8 qB1 = *(const short8*)(qbB + 32 + quad * 8);

  f32x4 oA[4], oB[4];
  {
    f32x4 z = {0.f, 0.f, 0.f, 0.f};
    #pragma unroll
    for (int dt = 0; dt < 4; ++dt) { oA[dt] = z; oB[dt] = z; }
  }
  float mA = -1e30f, lA = 0.f, mB = -1e30f, lB = 0.f;

  u16* pwA = Ps + (wave * 2 + 0) * 16 * 72;
  u16* pwB = Ps + (wave * 2 + 1) * 16 * 72;
  const u16* kbase = k + (size_t)bh * 2048 * 64;
  const u16* vbase = vt + (size_t)bh * 64 * 2048;
  const int lastA = 2 * qt, lastB = 2 * qt + 1;

  for (int kt = 0; kt <= lastB; ++kt) {
    const u16* kb = kbase + (size_t)kt * 64 * 64;
    const u16* vb = vbase + kt * 64;
    #pragma unroll
    for (int i = 0; i < 2; ++i) {
      int c = i * 256 + tid;
      int row = c >> 3, cc = c & 7;
      *(uint4*)(&Ks[row * 72 + cc * 8]) = *(const uint4*)(kb + (size_t)row * 64 + cc * 8);
      *(uint4*)(&Vs[row * 72 + cc * 8]) = *(const uint4*)(vb + (size_t)row * 2048 + cc * 8);
    }
    __syncthreads();

    // S^T for both groups; kf loads shared
    f32x4 sA[4], sB[4];
    #pragma unroll
    for (int nt = 0; nt < 4; ++nt) {
      short8 kf0 = *(const short8*)(&Ks[(nt * 16 + l16) * 72 + quad * 8]);
      short8 kf1 = *(const short8*)(&Ks[(nt * 16 + l16) * 72 + 32 + quad * 8]);
      f32x4 z4 = {0.f, 0.f, 0.f, 0.f};
      f32x4 tA = __builtin_amdgcn_mfma_f32_16x16x32_bf16(kf0, qA0, z4, 0, 0, 0);
      sA[nt] = __builtin_amdgcn_mfma_f32_16x16x32_bf16(kf1, qA1, tA, 0, 0, 0);
      f32x4 tB = __builtin_amdgcn_mfma_f32_16x16x32_bf16(kf0, qB0, z4, 0, 0, 0);
      sB[nt] = __builtin_amdgcn_mfma_f32_16x16x32_bf16(kf1, qB1, tB, 0, 0, 0);
    }

    const bool actA = (kt <= lastA);
    if (actA) {   // ---- group A: softmax + PV ----
      if (kt == lastA) {
        int q_loc = wave * 16 + l16;
        #pragma unroll
        for (int nt = 0; nt < 4; ++nt)
          #pragma unroll
          for (int r = 0; r < 4; ++r)
            if (nt * 16 + quad * 4 + r > q_loc) sA[nt][r] = -1e30f;
      }
      float mx = -1e30f;
      #pragma unroll
      for (int nt = 0; nt < 4; ++nt)
        #pragma unroll
        for (int r = 0; r < 4; ++r) mx = fmaxf(mx, sA[nt][r]);
      mx = fmaxf(mx, __shfl_xor(mx, 16));
      mx = fmaxf(mx, __shfl_xor(mx, 32));
      float mnew = fmaxf(mA, mx);
      float alpha = exp2f(mA - mnew);
      mA = mnew;
      Bc[wave][0][l16] = alpha;
      float sum = 0.f;
      #pragma unroll
      for (int nt = 0; nt < 4; ++nt) {
        #pragma unroll
        for (int r = 0; r < 4; ++r) {
          float p = exp2f(sA[nt][r] - mnew);
          sum += p;
          pwA[l16 * 72 + nt * 16 + quad * 4 + r] = (u16)f2bf_hu(p);
        }
      }
      sum += __shfl_xor(sum, 16);
      sum += __shfl_xor(sum, 32);
      lA = lA * alpha + sum;
      #pragma unroll
      for (int r = 0; r < 4; ++r) {
        float av = Bc[wave][0][quad * 4 + r];
        #pragma unroll
        for (int dt = 0; dt < 4; ++dt) oA[dt][r] *= av;
      }
      #pragma unroll
      for (int ks = 0; ks < 2; ++ks) {
        short8 pf = *(const short8*)(pwA + l16 * 72 + ks * 32 + quad * 8);
        #pragma unroll
        for (int dt = 0; dt < 4; ++dt) {
          short8 vf = *(const short8*)(&Vs[(dt * 16 + l16) * 72 + ks * 32 + quad * 8]);
          oA[dt] = __builtin_amdgcn_mfma_f32_16x16x32_bf16(pf, vf, oA[dt], 0, 0, 0);
        }
      }
    }

    {             // ---- group B: softmax + PV (always active) ----
      if (kt == lastB) {
        int q_loc = wave * 16 + l16;
        #pragma unroll
        for (int nt = 0; nt < 4; ++nt)
          #pragma unroll
          for (int r = 0; r < 4; ++r)
            if (nt * 16 + quad * 4 + r > q_loc) sB[nt][r] = -1e30f;
      }
      float mx = -1e30f;
      #pragma unroll
      for (int nt = 0; nt < 4; ++nt)
        #pragma unroll
        for (int r = 0; r < 4; ++r) mx = fmaxf(mx, sB[nt][r]);
      mx = fmaxf(mx, __shfl_xor(mx, 16));
      mx = fmaxf(mx, __shfl_xor(mx, 32));
      float mnew = fmaxf(mB, mx);
      float alpha = exp2f(mB - mnew);
      mB = mnew;
      Bc[wave][1][l16] = alpha;
      float sum = 0.f;
      #pragma unroll
      for (int nt = 0; nt < 4; ++nt) {
        #pragma unroll
        for (int r = 0; r < 4; ++r) {
          float p = exp2f(sB[nt][r] - mnew);
          sum += p;
          pwB[l16 * 72 + nt * 16 + quad * 4 + r] = (u16)f2bf_hu(p);
        }
      }
      sum += __shfl_xor(sum, 16);
      sum += __shfl_xor(sum, 32);
      lB = lB * alpha + sum;
      #pragma unroll
      for (int r = 0; r < 4; ++r) {
        float av = Bc[wave][1][quad * 4 + r];
        #pragma unroll
        for (int dt = 0; dt < 4; ++dt) oB[dt][r] *= av;
      }
      #pragma unroll
      for (int ks = 0; ks < 2; ++ks) {
        short8 pf = *(const short8*)(pwB + l16 * 72 + ks * 32 + quad * 8);
        #pragma unroll
        for (int dt = 0; dt < 4; ++dt) {
          short8 vf = *(const short8*)(&Vs[(dt * 16 + l16) * 72 + ks * 32 + quad * 8]);
          oB[dt] = __builtin_amdgcn_mfma_f32_16x16x32_bf16(pf, vf, oB[dt], 0, 0, 0);
        }
      }
    }
    __syncthreads();
  }

  // epilogue
  Lc[wave][0][l16] = lA;
  Lc[wave][1][l16] = lB;
  #pragma unroll
  for (int r = 0; r < 4; ++r) {
    float invA = 1.0f / Lc[wave][0][quad * 4 + r];
    float invB = 1.0f / Lc[wave][1][quad * 4 + r];
    int tA = qt * 128 + wave * 16 + quad * 4 + r;
    int tB = tA + 64;
    #pragma unroll
    for (int dt = 0; dt < 4; ++dt) {
      int d = dt * 16 + l16;
      y[(((size_t)b * 2048 + tA) * NH + h) * 64 + d] = (u16)f2bf(oA[dt][r] * invA);
      y[(((size_t)b * 2048 + tB) * NH + h) * 64 + d] = (u16)f2bf(oB[dt][r] * invB);
    }
  }
}

extern "C" void kernel_launch(void* const* d_in, const int* in_sizes, int n_in,
                              void* d_out, int out_size, void* d_ws, size_t ws_size,
                              hipStream_t stream) {
  const float* x  = (const float*)d_in[0];
  const float* Wq = (const float*)d_in[1];
  const float* bq = (const float*)d_in[2];
  const float* Wk = (const float*)d_in[3];
  const float* bk = (const float*)d_in[4];
  const float* Wv = (const float*)d_in[5];
  const float* bv = (const float*)d_in[6];
  const float* Wo = (const float*)d_in[7];
  const float* bo = (const float*)d_in[8];
  float* out = (float*)d_out;

  u16* ws  = (u16*)d_ws;
  u16* xb  = ws;                   // 8388608   x bf16 [8192][1024]
  u16* Wb  = ws + 8388608;         // 4x1048576 Wq|Wk|Wv|Wo bf16
  u16* qkv = ws + 12582912;        // 3x8388608 q|k|v [B,H,T,Dh] bf16
  u16* vt  = ws + 37748736;        // 8388608   v^T [B,H,Dh,T] bf16
  u16* y   = ws + 46137344;        // 8388608   attn out [B,T,H,Dh] bf16

  k_convert<<<dim3(12288), dim3(256), 0, stream>>>(x, Wq, Wk, Wv, Wo, ws);
  k_gemm_qkv<<<dim3(8, 64, 3), dim3(256), 0, stream>>>(xb, Wb, bq, bk, bv, qkv);
  k_vtrans<<<dim3(32, 64), dim3(256), 0, stream>>>(qkv + 2 * 8388608, vt);
  k_attn<<<dim3(16, 64), dim3(256), 0, stream>>>(qkv, qkv + 8388608, vt, y);
  k_gemm_out<<<dim3(8, 64), dim3(256), 0, stream>>>(y, Wb + 3 * 1048576, bo, out);
}